// Round 1
// 427.165 us; speedup vs baseline: 1.1026x; 1.1026x over previous
//
#include <hip/hip_runtime.h>
#include <stdint.h>

// Problem: B=16, S=512, H=2048, NH=16, NKV=4, HD=128
// out = Wo-proj( softmax(rope(q) @ rope(k)^T * hd^-.5) @ v )  with GQA rep=4
//
// ws layout (f16 intermediates):
//   x_h   [8192,2048]        @ 0
//   w_h   [3072,2048]        @ 33554432  (Wq 0..2047, Wk 2048..2559, Wv 2560..3071)
//   wo_h  [2048,2048]        @ 46137344
//   q     [16,16,512,128]    @ 54525952   (RoPE fused in gemm epilogue)
//   k     [16,4,512,128]     @ 88080384   (RoPE fused)
//   vt    [16,4,128,512]     @ 96468992   (V transposed)
//   attn  [8192,2048]        @ 104857600

typedef _Float16 f16;
typedef _Float16 f16x4 __attribute__((ext_vector_type(4)));
typedef _Float16 f16x8 __attribute__((ext_vector_type(8)));
typedef float f32x4 __attribute__((ext_vector_type(4)));

#define B_   16
#define S_   512
#define H_   2048
#define NH_  16
#define NKV_ 4
#define HD_  128
#define ATT_SCALE 0.08838834764831843f
#define LOG2_10000_DIV64 0.20762050593045952f

#define AS1 __attribute__((address_space(1)))
#define AS3 __attribute__((address_space(3)))

// async global->LDS, 16B/lane. LDS dest must be wave-uniform; HW adds lane*16.
__device__ __forceinline__ void async16(const void* g, const void* l) {
  __builtin_amdgcn_global_load_lds((const AS1 unsigned int*)(uintptr_t)g,
                                   (AS3 unsigned int*)(uintptr_t)l, 16, 0, 0);
}

// ---------------- fused fp32 -> f16 cast for all 5 inputs ----------------
__global__ __launch_bounds__(256) void cast_all(const float* __restrict__ x,
                                                const float* __restrict__ wq,
                                                const float* __restrict__ wk,
                                                const float* __restrict__ wv,
                                                const float* __restrict__ wo,
                                                f16* __restrict__ x_h,
                                                f16* __restrict__ w_h,
                                                f16* __restrict__ wo_h) {
  const int i = blockIdx.x * 256 + threadIdx.x;
  const float4* src;
  f16x4* dst;
  if (i < 4194304) {                 // x: 8192*2048
    src = (const float4*)x + i;            dst = (f16x4*)x_h + i;
  } else if (i < 5242880) {          // Wq: 2048*2048
    int j = i - 4194304;
    src = (const float4*)wq + j;           dst = (f16x4*)w_h + j;
  } else if (i < 5505024) {          // Wk: 512*2048
    int j = i - 5242880;
    src = (const float4*)wk + j;           dst = (f16x4*)w_h + 1048576 + j;
  } else if (i < 5767168) {          // Wv: 512*2048
    int j = i - 5505024;
    src = (const float4*)wv + j;           dst = (f16x4*)w_h + 1310720 + j;
  } else {                           // Wo: 2048*2048
    int j = i - 5767168;
    src = (const float4*)wo + j;           dst = (f16x4*)wo_h + j;
  }
  float4 v = *src;
  f16x4 o = {(f16)v.x, (f16)v.y, (f16)v.z, (f16)v.w};
  *dst = o;
}

// ---------------- 256x256 GEMM, BK=32, 8 waves, 4-deep LDS ring ----------
// Counted-vmcnt phase schedule (T3+T4+T5): per K-tile two phases of 16 MFMA
// wrapped in raw s_barrier + lgkmcnt(0) + setprio; staging of tile t+3 goes
// to ring buffer (t+3)&3 which is never concurrently read (distance-3 ring).
// vmcnt(8) once per tile keeps 2 tiles (8 loads/thread) in flight across
// barriers. BK=32 => 64B LDS rows: frag reads hit all 32 banks exactly 8x
// (bank floor for b128), no swizzle needed on either side.
//
// MODE 1: qkv projection. cols [0,2048)=Q, [2048,2560)=K (both RoPE'd),
//         [2560,3072)=V (stored transposed). Wave wn covers, within head
//         (wn>>1): d in {(wn&1)*32+[0,16), +16, +64, +80} so the RoPE pair
//         (d, d+64) is acc[mi][ni]/acc[mi][ni+2] in the same lane.
// MODE 0: out = attn @ Wo^T, fp32 output, plain col mapping.
template<int MODE>
__global__ __launch_bounds__(512, 2) void gemm256(const f16* __restrict__ A,
                                                  const f16* __restrict__ W,
                                                  f16* __restrict__ qo,
                                                  f16* __restrict__ ko,
                                                  f16* __restrict__ vto,
                                                  float* __restrict__ fout) {
  __shared__ __align__(16) f16 As[4][256 * 32];
  __shared__ __align__(16) f16 Bs[4][256 * 32];
  const int K = 2048;
  const int NT = 64;                       // K / 32
  const int m0 = blockIdx.x * 256;
  const int n0 = blockIdx.y * 256;
  const int tid = threadIdx.x;
  const int wave = tid >> 6, lane = tid & 63;
  const int quad = lane >> 4, l15 = lane & 15;
  const int wm = wave >> 2, wn = wave & 3;  // 2 x 4 wave grid, 128x64 / wave

  // staging: thread covers 16B chunks tid and tid+512 of each 16KB tile half
  // chunk L -> row L>>2 (0..255), 16B-slot L&3.  tid+512 => row+128.
  const f16* aptr = A + (size_t)(m0 + (tid >> 2)) * K + (tid & 3) * 8;
  const f16* bptr = W + (size_t)(n0 + (tid >> 2)) * K + (tid & 3) * 8;
  const int ldst = wave * 1024;            // this wave's chunk-group byte base

  f32x4 acc[8][4] = {};

  // prologue: stage tiles 0..2 into ring slots 0..2 (12 loads/thread)
#pragma unroll
  for (int t = 0; t < 3; ++t) {
    const int k0 = t * 32;
    async16(aptr + k0,             (const char*)&As[t][0] + ldst);
    async16(aptr + 128 * K + k0,   (const char*)&As[t][0] + 8192 + ldst);
    async16(bptr + k0,             (const char*)&Bs[t][0] + ldst);
    async16(bptr + 128 * K + k0,   (const char*)&Bs[t][0] + 8192 + ldst);
  }
  asm volatile("s_waitcnt vmcnt(8)" ::: "memory");  // tile 0 landed
  __builtin_amdgcn_s_barrier();

  for (int t = 0; t < NT; ++t) {
    const int buf = t & 3;
    const f16* Ab = &As[buf][0];
    const f16* Bb = &Bs[buf][0];
    const int sbuf = (t + 3) & 3;
    const int sk0 = (t + 3) * 32;
    f16x8 afr[4], bfr[4];

    // ---- phase 1: mi 0..3 x ni 0..3 ----
#pragma unroll
    for (int mi = 0; mi < 4; ++mi)
      afr[mi] = *reinterpret_cast<const f16x8*>(Ab + (wm * 128 + mi * 16 + l15) * 32 + quad * 8);
#pragma unroll
    for (int ni = 0; ni < 4; ++ni) {
      const int col = MODE ? ((wn >> 1) * 128 + (ni >> 1) * 64 + (wn & 1) * 32 + (ni & 1) * 16 + l15)
                           : (wn * 64 + ni * 16 + l15);
      bfr[ni] = *reinterpret_cast<const f16x8*>(Bb + col * 32 + quad * 8);
    }
    if (t + 3 < NT) {
      async16(aptr + sk0,           (const char*)&As[sbuf][0] + ldst);
      async16(aptr + 128 * K + sk0, (const char*)&As[sbuf][0] + 8192 + ldst);
    }
    __builtin_amdgcn_s_barrier();
    asm volatile("s_waitcnt lgkmcnt(0)" ::: "memory");
    __builtin_amdgcn_sched_barrier(0);
    __builtin_amdgcn_s_setprio(1);
#pragma unroll
    for (int mi = 0; mi < 4; ++mi)
#pragma unroll
      for (int ni = 0; ni < 4; ++ni)
        acc[mi][ni] = __builtin_amdgcn_mfma_f32_16x16x32_f16(afr[mi], bfr[ni], acc[mi][ni], 0, 0, 0);
    __builtin_amdgcn_s_setprio(0);
    __builtin_amdgcn_s_barrier();

    // ---- phase 2: mi 4..7 x ni 0..3 (bfr reused in-register) ----
#pragma unroll
    for (int mi = 0; mi < 4; ++mi)
      afr[mi] = *reinterpret_cast<const f16x8*>(Ab + (wm * 128 + (mi + 4) * 16 + l15) * 32 + quad * 8);
    if (t + 3 < NT) {
      async16(bptr + sk0,           (const char*)&Bs[sbuf][0] + ldst);
      async16(bptr + 128 * K + sk0, (const char*)&Bs[sbuf][0] + 8192 + ldst);
    }
    __builtin_amdgcn_s_barrier();
    asm volatile("s_waitcnt lgkmcnt(0)" ::: "memory");
    __builtin_amdgcn_sched_barrier(0);
    __builtin_amdgcn_s_setprio(1);
#pragma unroll
    for (int mi = 0; mi < 4; ++mi)
#pragma unroll
      for (int ni = 0; ni < 4; ++ni)
        acc[mi + 4][ni] = __builtin_amdgcn_mfma_f32_16x16x32_f16(afr[mi], bfr[ni], acc[mi + 4][ni], 0, 0, 0);
    __builtin_amdgcn_s_setprio(0);

    // end-of-group: tile t+1 must have landed; keep newer loads in flight
    if (t + 3 < NT)      asm volatile("s_waitcnt vmcnt(8)" ::: "memory");
    else if (t + 2 < NT) asm volatile("s_waitcnt vmcnt(4)" ::: "memory");
    else if (t + 1 < NT) asm volatile("s_waitcnt vmcnt(0)" ::: "memory");
    __builtin_amdgcn_s_barrier();
  }

  // ---------------- epilogues ----------------
  if constexpr (MODE == 1) {
    const int b_ = m0 >> 9;  // batch (uniform per block; 256 | 512)
    if (n0 >= 2560) {
      // ---- V: no rope, store transposed [b, kh, d, s] ----
      const int h = ((n0 - 2560) >> 7) + (wn >> 1);
      f16* vb = vto + ((size_t)b_ * NKV_ + h) * HD_ * S_;
#pragma unroll
      for (int mi = 0; mi < 8; ++mi)
#pragma unroll
        for (int r = 0; r < 4; ++r) {
          const int s = (m0 + wm * 128 + mi * 16 + quad * 4 + r) & 511;
#pragma unroll
          for (int ni = 0; ni < 4; ++ni) {
            const int d = (ni >> 1) * 64 + (wn & 1) * 32 + (ni & 1) * 16 + l15;
            vb[(size_t)d * S_ + s] = (f16)acc[mi][ni][r];
          }
        }
    } else {
      // ---- Q or K: fused RoPE, store [b, h, s, d] ----
      f16* ob = (n0 < 2048)
          ? (qo + ((size_t)b_ * NH_ + (n0 >> 7) + (wn >> 1)) * S_ * HD_)
          : (ko + ((size_t)b_ * NKV_ + ((n0 - 2048) >> 7) + (wn >> 1)) * S_ * HD_);
      float invf[2];
#pragma unroll
      for (int ni = 0; ni < 2; ++ni)
        invf[ni] = exp2f((float)((wn & 1) * 32 + ni * 16 + l15) * -LOG2_10000_DIV64);
#pragma unroll
      for (int mi = 0; mi < 8; ++mi)
#pragma unroll
        for (int r = 0; r < 4; ++r) {
          const int s = (m0 + wm * 128 + mi * 16 + quad * 4 + r) & 511;
          const size_t rb = (size_t)s * HD_;
#pragma unroll
          for (int ni = 0; ni < 2; ++ni) {
            const int d = (wn & 1) * 32 + ni * 16 + l15;  // 0..63
            float sn, cs;
            __sincosf((float)s * invf[ni], &sn, &cs);
            const float x1 = acc[mi][ni][r], x2 = acc[mi][ni + 2][r];
            ob[rb + d] = (f16)(x1 * cs - x2 * sn);
            ob[rb + d + 64] = (f16)(x2 * cs + x1 * sn);
          }
        }
    }
  } else {
    // ---- fp32 output: out = attn @ Wo^T ----
#pragma unroll
    for (int mi = 0; mi < 8; ++mi)
#pragma unroll
      for (int ni = 0; ni < 4; ++ni) {
        const int ncol = n0 + wn * 64 + ni * 16 + l15;
#pragma unroll
        for (int r = 0; r < 4; ++r) {
          const int mrow = m0 + wm * 128 + mi * 16 + quad * 4 + r;
          fout[(size_t)mrow * 2048 + ncol] = acc[mi][ni][r];
        }
      }
  }
}

// ---------------- flash attention ----------------
// 512 thr = 8 waves; wave owns 16 q-rows. Q/K/V tiles XOR-swizzled in LDS
// (256B rows, chunk c at slot c^(r&15)) -> <=2-way bank aliasing (free).
__global__ __launch_bounds__(512) void attn_kernel(const f16* __restrict__ q,
                                                   const f16* __restrict__ k,
                                                   const f16* __restrict__ vt,
                                                   f16* __restrict__ out) {
  __shared__ __align__(16) f16 Qs[128 * 128];
  __shared__ __align__(16) f16 Ks[128 * 128];
  __shared__ __align__(16) f16 Vs[128 * 128];   // [d][key]
  __shared__ __align__(16) f16 Ps[8][16 * 136];

  const int qt = blockIdx.x, h = blockIdx.y, b = blockIdx.z;
  const int kvh = h >> 2;
  const int tid = threadIdx.x;
  const int wave = tid >> 6, lane = tid & 63;
  const int quad = lane >> 4, l15 = lane & 15;
  const int sm0 = wave * 16;

  const f16* qbase = q + (((size_t)b * NH_ + h) * S_ + qt * 128) * HD_;
  const f16* kbase = k + ((size_t)b * NKV_ + kvh) * S_ * HD_;
  const f16* vbase = vt + ((size_t)b * NKV_ + kvh) * HD_ * S_;

  // stage Q tile, swizzled: LDS chunk L holds global chunk (r, (L&15)^(r&15))
#pragma unroll
  for (int i = 0; i < 4; ++i) {
    const int L = wave * 256 + i * 64 + lane;
    const int r = L >> 4;
    const int c = (L & 15) ^ (r & 15);
    async16(qbase + (size_t)r * HD_ + c * 8, (const char*)Qs + (size_t)(wave * 256 + i * 64) * 16);
  }

  f32x4 O[8] = {};
  float mrun[4], lrun[4];
#pragma unroll
  for (int r = 0; r < 4; ++r) { mrun[r] = -3.0e38f; lrun[r] = 0.f; }

  for (int j = 0; j < 4; ++j) {
    if (j) __syncthreads();  // waves done reading previous K/V tiles
#pragma unroll
    for (int i = 0; i < 4; ++i) {
      const int L = wave * 256 + i * 64 + lane;
      const int r = L >> 4;
      const int c = (L & 15) ^ (r & 15);
      async16(kbase + (size_t)(j * 128 + r) * HD_ + c * 8,
              (const char*)Ks + (size_t)(wave * 256 + i * 64) * 16);
      async16(vbase + (size_t)r * S_ + j * 128 + c * 8,
              (const char*)Vs + (size_t)(wave * 256 + i * 64) * 16);
    }
    __syncthreads();  // drains vmcnt -> tiles visible

    // S = Q @ K^T (16 q-rows per wave x 128 keys)
    f32x4 Sc[8] = {};
#pragma unroll
    for (int ks = 0; ks < 4; ++ks) {
      f16x8 aq, bk[8];
      aq = *reinterpret_cast<const f16x8*>(Qs + ((sm0 + l15) * 16 + (((ks * 4 + quad) ^ l15))) * 8);
#pragma unroll
      for (int ni = 0; ni < 8; ++ni)
        bk[ni] = *reinterpret_cast<const f16x8*>(Ks + ((ni * 16 + l15) * 16 + ((ks * 4 + quad) ^ l15)) * 8);
#pragma unroll
      for (int ni = 0; ni < 8; ++ni)
        Sc[ni] = __builtin_amdgcn_mfma_f32_16x16x32_f16(aq, bk[ni], Sc[ni], 0, 0, 0);
    }

    // online softmax (C-layout: row=quad*4+r, col=ni*16+l15)
#pragma unroll
    for (int r = 0; r < 4; ++r) {
      float mx = -3.0e38f;
#pragma unroll
      for (int ni = 0; ni < 8; ++ni) mx = fmaxf(mx, Sc[ni][r]);
      mx *= ATT_SCALE;
#pragma unroll
      for (int off = 1; off < 16; off <<= 1) mx = fmaxf(mx, __shfl_xor(mx, off));
      const float mnew = fmaxf(mrun[r], mx);
      const float alpha = __expf(mrun[r] - mnew);
      float rs = 0.f;
#pragma unroll
      for (int ni = 0; ni < 8; ++ni) {
        const float pv = __expf(Sc[ni][r] * ATT_SCALE - mnew);
        Sc[ni][r] = pv;
        rs += pv;
      }
#pragma unroll
      for (int off = 1; off < 16; off <<= 1) rs += __shfl_xor(rs, off);
      lrun[r] = lrun[r] * alpha + rs;
      mrun[r] = mnew;
#pragma unroll
      for (int ni = 0; ni < 8; ++ni) O[ni][r] *= alpha;
#pragma unroll
      for (int ni = 0; ni < 8; ++ni)
        Ps[wave][(quad * 4 + r) * 136 + ni * 16 + l15] = (f16)Sc[ni][r];
    }

    // O += P @ V (per-wave P, no barrier needed; Vs rows are d, k-dim = key)
#pragma unroll
    for (int ks = 0; ks < 4; ++ks) {
      f16x8 ap, bv[8];
      ap = *reinterpret_cast<const f16x8*>(&Ps[wave][l15 * 136 + ks * 32 + quad * 8]);
#pragma unroll
      for (int ni = 0; ni < 8; ++ni)
        bv[ni] = *reinterpret_cast<const f16x8*>(Vs + ((ni * 16 + l15) * 16 + ((ks * 4 + quad) ^ l15)) * 8);
#pragma unroll
      for (int ni = 0; ni < 8; ++ni)
        O[ni] = __builtin_amdgcn_mfma_f32_16x16x32_f16(ap, bv[ni], O[ni], 0, 0, 0);
    }
  }

  // epilogue: normalize, write attn[b, s, h*128 + d]
#pragma unroll
  for (int r = 0; r < 4; ++r) {
    const float inv = 1.f / lrun[r];
    const int srow = qt * 128 + sm0 + quad * 4 + r;
#pragma unroll
    for (int ni = 0; ni < 8; ++ni)
      out[((size_t)b * S_ + srow) * H_ + h * HD_ + ni * 16 + l15] = (f16)(O[ni][r] * inv);
  }
}

extern "C" void kernel_launch(void* const* d_in, const int* in_sizes, int n_in,
                              void* d_out, int out_size, void* d_ws, size_t ws_size,
                              hipStream_t stream) {
  const float* x = (const float*)d_in[0];
  const float* Wq = (const float*)d_in[1];
  const float* Wk = (const float*)d_in[2];
  const float* Wv = (const float*)d_in[3];
  const float* Wo = (const float*)d_in[4];
  float* out = (float*)d_out;
  char* ws = (char*)d_ws;

  f16* x_h  = (f16*)(ws + 0);
  f16* w_h  = (f16*)(ws + 33554432);
  f16* wo_h = (f16*)(ws + 46137344);
  f16* qb   = (f16*)(ws + 54525952);
  f16* kb   = (f16*)(ws + 88080384);
  f16* vtb  = (f16*)(ws + 96468992);
  f16* attn = (f16*)(ws + 104857600);  // needs ws_size >= 138412032

  cast_all<<<26624, 256, 0, stream>>>(x, Wq, Wk, Wv, Wo, x_h, w_h, wo_h);
  gemm256<1><<<dim3(32, 12), 512, 0, stream>>>(x_h, w_h, qb, kb, vtb, nullptr);
  attn_kernel<<<dim3(4, 16, 16), 512, 0, stream>>>(qb, kb, vtb, attn);
  gemm256<0><<<dim3(32, 8), 512, 0, stream>>>(attn, wo_h, nullptr, nullptr, nullptr, out);
}

// Round 2
// 381.686 us; speedup vs baseline: 1.2340x; 1.1192x over previous
//
#include <hip/hip_runtime.h>
#include <stdint.h>

// Problem: B=16, S=512, H=2048, NH=16, NKV=4, HD=128
// out = Wo-proj( softmax(rope(q) @ rope(k)^T * hd^-.5) @ v )  with GQA rep=4
//
// ws layout (f16 intermediates):
//   x_h   [8192,2048]        @ 0
//   w_h   [3072,2048]        @ 33554432  (Wq 0..2047, Wk 2048..2559, Wv 2560..3071)
//   wo_h  [2048,2048]        @ 46137344
//   q     [16,16,512,128]    @ 54525952   (RoPE fused in gemm epilogue)
//   k     [16,4,512,128]     @ 88080384   (RoPE fused)
//   vt    [16,4,128,512]     @ 96468992   (V transposed)
//   attn  [8192,2048]        @ 104857600

typedef _Float16 f16;
typedef _Float16 f16x4 __attribute__((ext_vector_type(4)));
typedef _Float16 f16x8 __attribute__((ext_vector_type(8)));
typedef float f32x4 __attribute__((ext_vector_type(4)));

#define B_   16
#define S_   512
#define H_   2048
#define NH_  16
#define NKV_ 4
#define HD_  128
#define ATT_SCALE 0.08838834764831843f
#define LOG2_10000_DIV64 0.20762050593045952f

#define AS1 __attribute__((address_space(1)))
#define AS3 __attribute__((address_space(3)))

// async global->LDS, 16B/lane. LDS dest must be wave-uniform; HW adds lane*16.
__device__ __forceinline__ void async16(const void* g, const void* l) {
  __builtin_amdgcn_global_load_lds((const AS1 unsigned int*)(uintptr_t)g,
                                   (AS3 unsigned int*)(uintptr_t)l, 16, 0, 0);
}

// ---------------- fused fp32 -> f16 cast for all 5 inputs ----------------
__global__ __launch_bounds__(256) void cast_all(const float* __restrict__ x,
                                                const float* __restrict__ wq,
                                                const float* __restrict__ wk,
                                                const float* __restrict__ wv,
                                                const float* __restrict__ wo,
                                                f16* __restrict__ x_h,
                                                f16* __restrict__ w_h,
                                                f16* __restrict__ wo_h) {
  const int i = blockIdx.x * 256 + threadIdx.x;
  const float4* src;
  f16x4* dst;
  if (i < 4194304) {                 // x: 8192*2048
    src = (const float4*)x + i;            dst = (f16x4*)x_h + i;
  } else if (i < 5242880) {          // Wq: 2048*2048
    int j = i - 4194304;
    src = (const float4*)wq + j;           dst = (f16x4*)w_h + j;
  } else if (i < 5505024) {          // Wk: 512*2048
    int j = i - 5242880;
    src = (const float4*)wk + j;           dst = (f16x4*)w_h + 1048576 + j;
  } else if (i < 5767168) {          // Wv: 512*2048
    int j = i - 5505024;
    src = (const float4*)wv + j;           dst = (f16x4*)w_h + 1310720 + j;
  } else {                           // Wo: 2048*2048
    int j = i - 5767168;
    src = (const float4*)wo + j;           dst = (f16x4*)wo_h + j;
  }
  float4 v = *src;
  f16x4 o = {(f16)v.x, (f16)v.y, (f16)v.z, (f16)v.w};
  *dst = o;
}

// ---------------- 256x128 GEMM, BK=64, 8 waves, 3-deep LDS ring ----------
// Wave grid 4M x 2N, wave tile 64x64 (cols split 32+32 for RoPE pairing).
// Per K-tile: 2 phases; phase P computes MFMA(ks=P) from frags loaded last
// phase while THIS phase's ds_reads are in flight (lgkmcnt(8) counted wait)
// -> LDS read latency hides under MFMA. Ring-3: stage tile t+2 into buf of
// t-1 (readers fenced by end-of-tile barrier). vmcnt(3) mid-tile (counted,
// never 0 until the tail) keeps 9 global loads in flight across barriers.
// LDS rows = 128B: frag slot swizzle (ks*4+quad)^(l15&7) with matching
// pre-swizzled global source -> 4 lanes per 16B granule per half-wave
// (conflict-free); staging LDS-linear per global_load_lds requirement.
//
// MODE 1: qkv projection. n0<2048: Q head n0>>7 (RoPE); n0<2560: K head
//         (RoPE); else V head (store transposed). Cols of a wave:
//         {wn*32+[0,32)} u {64+wn*32+[0,32)} so RoPE pair (d, d+64) is
//         acc[mi][ni] / acc[mi][ni+2] in the same lane.
// MODE 0: out = attn @ Wo^T, fp32 output (same col split, plain write).
template<int MODE>
__global__ __launch_bounds__(512, 2) void gemm_k(const f16* __restrict__ A,
                                                 const f16* __restrict__ W,
                                                 f16* __restrict__ qo,
                                                 f16* __restrict__ ko,
                                                 f16* __restrict__ vto,
                                                 float* __restrict__ fout) {
  __shared__ __align__(16) f16 As[3][256 * 64];   // 3 x 32 KiB
  __shared__ __align__(16) f16 Bs[3][128 * 64];   // 3 x 16 KiB  (total 144 KiB)
  const int K = 2048;
  const int NT = 32;                       // K / 64
  const int m0 = blockIdx.x * 256;
  const int n0 = blockIdx.y * 128;
  const int tid = threadIdx.x;
  const int wave = tid >> 6, lane = tid & 63;
  const int quad = lane >> 4, l15 = lane & 15;
  const int wm = wave >> 1, wn = wave & 1;  // 4M x 2N, 64x64 per wave

  // staging pointers, global source pre-swizzled: LDS chunk L=(r,s) holds
  // global k-chunk s^(r&7)  (involution; ds_read applies the same XOR)
  const f16* aptr[4];
  const f16* bptr[2];
#pragma unroll
  for (int i = 0; i < 4; ++i) {
    const int L = i * 512 + wave * 64 + lane;
    const int r = L >> 3, s = L & 7;
    aptr[i] = A + (size_t)(m0 + r) * K + (s ^ (r & 7)) * 8;
  }
#pragma unroll
  for (int i = 0; i < 2; ++i) {
    const int L = i * 512 + wave * 64 + lane;
    const int r = L >> 3, s = L & 7;
    bptr[i] = W + (size_t)(n0 + r) * K + (s ^ (r & 7)) * 8;
  }
  const int ldsw = wave * 1024;            // wave's chunk-group byte base

  f32x4 acc[4][4] = {};
  f16x8 aC[4], bC[4], aN[4], bN[4];

  auto ldA = [&](f16x8* d, const f16* base, int ks) {
#pragma unroll
    for (int mi = 0; mi < 4; ++mi) {
      const int row = wm * 64 + mi * 16 + l15;
      const int slot = (ks * 4 + quad) ^ (l15 & 7);
      d[mi] = *reinterpret_cast<const f16x8*>(base + row * 64 + slot * 8);
    }
  };
  auto ldB = [&](f16x8* d, const f16* base, int ks) {
#pragma unroll
    for (int ni = 0; ni < 4; ++ni) {
      const int col = wn * 32 + (ni >> 1) * 64 + (ni & 1) * 16 + l15;
      const int slot = (ks * 4 + quad) ^ (l15 & 7);
      d[ni] = *reinterpret_cast<const f16x8*>(base + col * 64 + slot * 8);
    }
  };
  auto mfma16 = [&](const f16x8* Af, const f16x8* Bf) {
#pragma unroll
    for (int mi = 0; mi < 4; ++mi)
#pragma unroll
      for (int ni = 0; ni < 4; ++ni)
        acc[mi][ni] = __builtin_amdgcn_mfma_f32_16x16x32_f16(Af[mi], Bf[ni], acc[mi][ni], 0, 0, 0);
  };

  // prologue: stage tiles 0,1 (12 loads/thread)
#pragma unroll
  for (int t = 0; t < 2; ++t) {
#pragma unroll
    for (int i = 0; i < 4; ++i)
      async16(aptr[i] + t * 64, (const char*)&As[t][0] + i * 8192 + ldsw);
#pragma unroll
    for (int i = 0; i < 2; ++i)
      async16(bptr[i] + t * 64, (const char*)&Bs[t][0] + i * 8192 + ldsw);
  }
  asm volatile("s_waitcnt vmcnt(6)" ::: "memory");  // tile 0 landed
  __builtin_amdgcn_s_barrier();
  ldA(aC, &As[0][0], 0);                   // 8 reads in flight entering loop
  ldB(bC, &Bs[0][0], 0);

  for (int t = 0; t < NT; ++t) {
    const int buf = t % 3, bufn = (t + 1) % 3, bufs = (t + 2) % 3;
    const int sk = (t + 2) * 64;

    // ---- P0: MFMA ks=0 while ks=1 reads + 3 stage loads are in flight ----
    ldA(aN, &As[buf][0], 1);
    ldB(bN, &Bs[buf][0], 1);
    if (t + 2 < NT) {
      async16(aptr[0] + sk, (const char*)&As[bufs][0] + 0 * 8192 + ldsw);
      async16(aptr[1] + sk, (const char*)&As[bufs][0] + 1 * 8192 + ldsw);
      async16(bptr[0] + sk, (const char*)&Bs[bufs][0] + 0 * 8192 + ldsw);
    }
    asm volatile("s_waitcnt lgkmcnt(8)" ::: "memory");  // aC/bC ready
    __builtin_amdgcn_sched_barrier(0);
    __builtin_amdgcn_s_setprio(1);
    mfma16(aC, bC);
    __builtin_amdgcn_s_setprio(0);

    // ---- MID: tile t+1 resident (counted vmcnt, all waves) ----
    if (t + 1 < NT) {
      if (t + 2 < NT) asm volatile("s_waitcnt vmcnt(3)" ::: "memory");
      else            asm volatile("s_waitcnt vmcnt(0)" ::: "memory");
      __builtin_amdgcn_s_barrier();
    }

    // ---- P1: MFMA ks=1 while next-tile ks=0 reads + 3 stages in flight ----
    if (t + 1 < NT) {
      ldA(aC, &As[bufn][0], 0);
      ldB(bC, &Bs[bufn][0], 0);
    }
    if (t + 2 < NT) {
      async16(aptr[2] + sk, (const char*)&As[bufs][0] + 2 * 8192 + ldsw);
      async16(aptr[3] + sk, (const char*)&As[bufs][0] + 3 * 8192 + ldsw);
      async16(bptr[1] + sk, (const char*)&Bs[bufs][0] + 1 * 8192 + ldsw);
    }
    if (t + 1 < NT) asm volatile("s_waitcnt lgkmcnt(8)" ::: "memory");  // aN/bN ready
    else            asm volatile("s_waitcnt lgkmcnt(0)" ::: "memory");
    __builtin_amdgcn_sched_barrier(0);
    __builtin_amdgcn_s_setprio(1);
    mfma16(aN, bN);
    __builtin_amdgcn_s_setprio(0);
    // end-of-tile: all waves past their reads of buf (t-1)%3 == bufs before
    // next iteration's stage issues overwrite it
    if (t + 1 < NT) __builtin_amdgcn_s_barrier();
  }

  // ---------------- epilogues ----------------
  if constexpr (MODE == 1) {
    const int b_ = m0 >> 9;  // batch (uniform per block; 256 | 512)
    if (n0 >= 2560) {
      // ---- V: no rope, store transposed [b, kh, d, s] ----
      const int h = (n0 - 2560) >> 7;
      f16* vb = vto + ((size_t)b_ * NKV_ + h) * HD_ * S_;
#pragma unroll
      for (int mi = 0; mi < 4; ++mi)
#pragma unroll
        for (int r = 0; r < 4; ++r) {
          const int s = (m0 + wm * 64 + mi * 16 + quad * 4 + r) & 511;
#pragma unroll
          for (int ni = 0; ni < 4; ++ni) {
            const int d = (ni >> 1) * 64 + wn * 32 + (ni & 1) * 16 + l15;
            vb[(size_t)d * S_ + s] = (f16)acc[mi][ni][r];
          }
        }
    } else {
      // ---- Q or K: fused RoPE, store [b, h, s, d] ----
      f16* ob = (n0 < 2048)
          ? (qo + ((size_t)b_ * NH_ + (n0 >> 7)) * S_ * HD_)
          : (ko + ((size_t)b_ * NKV_ + ((n0 - 2048) >> 7)) * S_ * HD_);
      float invf[2];
#pragma unroll
      for (int ni = 0; ni < 2; ++ni)
        invf[ni] = exp2f((float)(wn * 32 + ni * 16 + l15) * -LOG2_10000_DIV64);
#pragma unroll
      for (int mi = 0; mi < 4; ++mi)
#pragma unroll
        for (int r = 0; r < 4; ++r) {
          const int s = (m0 + wm * 64 + mi * 16 + quad * 4 + r) & 511;
          const size_t rb = (size_t)s * HD_;
#pragma unroll
          for (int ni = 0; ni < 2; ++ni) {
            const int d = wn * 32 + ni * 16 + l15;  // 0..63
            float sn, cs;
            __sincosf((float)s * invf[ni], &sn, &cs);
            const float x1 = acc[mi][ni][r], x2 = acc[mi][ni + 2][r];
            ob[rb + d] = (f16)(x1 * cs - x2 * sn);
            ob[rb + d + 64] = (f16)(x2 * cs + x1 * sn);
          }
        }
    }
  } else {
    // ---- fp32 output: out = attn @ Wo^T ----
#pragma unroll
    for (int mi = 0; mi < 4; ++mi)
#pragma unroll
      for (int ni = 0; ni < 4; ++ni) {
        const int ncol = n0 + wn * 32 + (ni >> 1) * 64 + (ni & 1) * 16 + l15;
#pragma unroll
        for (int r = 0; r < 4; ++r) {
          const int mrow = m0 + wm * 64 + mi * 16 + quad * 4 + r;
          fout[(size_t)mrow * 2048 + ncol] = acc[mi][ni][r];
        }
      }
  }
}

// ---------------- flash attention ----------------
// 512 thr = 8 waves; wave owns 16 q-rows. Q/K/V tiles XOR-swizzled in LDS
// (256B rows, chunk c at slot c^(r&15)) -> <=2-way bank aliasing (free).
__global__ __launch_bounds__(512) void attn_kernel(const f16* __restrict__ q,
                                                   const f16* __restrict__ k,
                                                   const f16* __restrict__ vt,
                                                   f16* __restrict__ out) {
  __shared__ __align__(16) f16 Qs[128 * 128];
  __shared__ __align__(16) f16 Ks[128 * 128];
  __shared__ __align__(16) f16 Vs[128 * 128];   // [d][key]
  __shared__ __align__(16) f16 Ps[8][16 * 136];

  const int qt = blockIdx.x, h = blockIdx.y, b = blockIdx.z;
  const int kvh = h >> 2;
  const int tid = threadIdx.x;
  const int wave = tid >> 6, lane = tid & 63;
  const int quad = lane >> 4, l15 = lane & 15;
  const int sm0 = wave * 16;

  const f16* qbase = q + (((size_t)b * NH_ + h) * S_ + qt * 128) * HD_;
  const f16* kbase = k + ((size_t)b * NKV_ + kvh) * S_ * HD_;
  const f16* vbase = vt + ((size_t)b * NKV_ + kvh) * HD_ * S_;

  // stage Q tile, swizzled: LDS chunk L holds global chunk (r, (L&15)^(r&15))
#pragma unroll
  for (int i = 0; i < 4; ++i) {
    const int L = wave * 256 + i * 64 + lane;
    const int r = L >> 4;
    const int c = (L & 15) ^ (r & 15);
    async16(qbase + (size_t)r * HD_ + c * 8, (const char*)Qs + (size_t)(wave * 256 + i * 64) * 16);
  }

  f32x4 O[8] = {};
  float mrun[4], lrun[4];
#pragma unroll
  for (int r = 0; r < 4; ++r) { mrun[r] = -3.0e38f; lrun[r] = 0.f; }

  for (int j = 0; j < 4; ++j) {
    if (j) __syncthreads();  // waves done reading previous K/V tiles
#pragma unroll
    for (int i = 0; i < 4; ++i) {
      const int L = wave * 256 + i * 64 + lane;
      const int r = L >> 4;
      const int c = (L & 15) ^ (r & 15);
      async16(kbase + (size_t)(j * 128 + r) * HD_ + c * 8,
              (const char*)Ks + (size_t)(wave * 256 + i * 64) * 16);
      async16(vbase + (size_t)r * S_ + j * 128 + c * 8,
              (const char*)Vs + (size_t)(wave * 256 + i * 64) * 16);
    }
    __syncthreads();  // drains vmcnt -> tiles visible

    // S = Q @ K^T (16 q-rows per wave x 128 keys)
    f32x4 Sc[8] = {};
#pragma unroll
    for (int ks = 0; ks < 4; ++ks) {
      f16x8 aq, bk[8];
      aq = *reinterpret_cast<const f16x8*>(Qs + ((sm0 + l15) * 16 + (((ks * 4 + quad) ^ l15))) * 8);
#pragma unroll
      for (int ni = 0; ni < 8; ++ni)
        bk[ni] = *reinterpret_cast<const f16x8*>(Ks + ((ni * 16 + l15) * 16 + ((ks * 4 + quad) ^ l15)) * 8);
#pragma unroll
      for (int ni = 0; ni < 8; ++ni)
        Sc[ni] = __builtin_amdgcn_mfma_f32_16x16x32_f16(aq, bk[ni], Sc[ni], 0, 0, 0);
    }

    // online softmax (C-layout: row=quad*4+r, col=ni*16+l15)
#pragma unroll
    for (int r = 0; r < 4; ++r) {
      float mx = -3.0e38f;
#pragma unroll
      for (int ni = 0; ni < 8; ++ni) mx = fmaxf(mx, Sc[ni][r]);
      mx *= ATT_SCALE;
#pragma unroll
      for (int off = 1; off < 16; off <<= 1) mx = fmaxf(mx, __shfl_xor(mx, off));
      const float mnew = fmaxf(mrun[r], mx);
      const float alpha = __expf(mrun[r] - mnew);
      float rs = 0.f;
#pragma unroll
      for (int ni = 0; ni < 8; ++ni) {
        const float pv = __expf(Sc[ni][r] * ATT_SCALE - mnew);
        Sc[ni][r] = pv;
        rs += pv;
      }
#pragma unroll
      for (int off = 1; off < 16; off <<= 1) rs += __shfl_xor(rs, off);
      lrun[r] = lrun[r] * alpha + rs;
      mrun[r] = mnew;
#pragma unroll
      for (int ni = 0; ni < 8; ++ni) O[ni][r] *= alpha;
#pragma unroll
      for (int ni = 0; ni < 8; ++ni)
        Ps[wave][(quad * 4 + r) * 136 + ni * 16 + l15] = (f16)Sc[ni][r];
    }

    // O += P @ V (per-wave P, no barrier needed; Vs rows are d, k-dim = key)
#pragma unroll
    for (int ks = 0; ks < 4; ++ks) {
      f16x8 ap, bv[8];
      ap = *reinterpret_cast<const f16x8*>(&Ps[wave][l15 * 136 + ks * 32 + quad * 8]);
#pragma unroll
      for (int ni = 0; ni < 8; ++ni)
        bv[ni] = *reinterpret_cast<const f16x8*>(Vs + ((ni * 16 + l15) * 16 + ((ks * 4 + quad) ^ l15)) * 8);
#pragma unroll
      for (int ni = 0; ni < 8; ++ni)
        O[ni] = __builtin_amdgcn_mfma_f32_16x16x32_f16(ap, bv[ni], O[ni], 0, 0, 0);
    }
  }

  // epilogue: normalize, write attn[b, s, h*128 + d]
#pragma unroll
  for (int r = 0; r < 4; ++r) {
    const float inv = 1.f / lrun[r];
    const int srow = qt * 128 + sm0 + quad * 4 + r;
#pragma unroll
    for (int ni = 0; ni < 8; ++ni)
      out[((size_t)b * S_ + srow) * H_ + h * HD_ + ni * 16 + l15] = (f16)(O[ni][r] * inv);
  }
}

extern "C" void kernel_launch(void* const* d_in, const int* in_sizes, int n_in,
                              void* d_out, int out_size, void* d_ws, size_t ws_size,
                              hipStream_t stream) {
  const float* x = (const float*)d_in[0];
  const float* Wq = (const float*)d_in[1];
  const float* Wk = (const float*)d_in[2];
  const float* Wv = (const float*)d_in[3];
  const float* Wo = (const float*)d_in[4];
  float* out = (float*)d_out;
  char* ws = (char*)d_ws;

  f16* x_h  = (f16*)(ws + 0);
  f16* w_h  = (f16*)(ws + 33554432);
  f16* wo_h = (f16*)(ws + 46137344);
  f16* qb   = (f16*)(ws + 54525952);
  f16* kb   = (f16*)(ws + 88080384);
  f16* vtb  = (f16*)(ws + 96468992);
  f16* attn = (f16*)(ws + 104857600);  // needs ws_size >= 138412032

  cast_all<<<26624, 256, 0, stream>>>(x, Wq, Wk, Wv, Wo, x_h, w_h, wo_h);
  gemm_k<1><<<dim3(32, 24), 512, 0, stream>>>(x_h, w_h, qb, kb, vtb, nullptr);
  attn_kernel<<<dim3(4, 16, 16), 512, 0, stream>>>(qb, kb, vtb, attn);
  gemm_k<0><<<dim3(32, 16), 512, 0, stream>>>(attn, wo_h, nullptr, nullptr, nullptr, out);
}